// Round 2
// baseline (208.230 us; speedup 1.0000x reference)
//
#include <hip/hip_runtime.h>

#define BS      4096
#define SEGLEN  8192
#define LAMBDA1 8e-05f
#define LAMBDA2 8e-05f

typedef float f4 __attribute__((ext_vector_type(4)));

// ---------------------------------------------------------------------------
// Kernel 1: per-row stats. 2048 blocks (256 threads), TWO rows per block.
//   smooth[row] = sum_{c=0..SEGLEN-2} (s[c+1]-s[c])^2
//   spars [row] = sum_c s[c]
//   ms    [row] = argmax_c s[c]   (FIRST occurrence on ties, like np.argmax)
//
// R2 structural change: both rows' 8 dwordx4 loads (16 total / thread, 256 B)
// are issued back-to-back before ANY compute. The block's single
// vmcnt(0)+barrier now amortizes over 64 KB instead of 32 KB, halving the
// number of per-block HBM-latency ramps and cutting the grid from 4096 to
// 2048 blocks (one dispatch round at 8 blocks/CU). Boundary "next" elements
// come from __shfl_down + a tiny LDS table, so the 16 dwordx4 are the only
// global reads (nontemporal: streamed once, evict-first).
// ---------------------------------------------------------------------------
#define RPB 2
#define NB  (BS / RPB)   // 2048 blocks

__global__ __launch_bounds__(256) void row_stats(const float* __restrict__ scores,
                                                 float* __restrict__ smooth,
                                                 float* __restrict__ spars,
                                                 int*   __restrict__ ms,
                                                 float* __restrict__ out) {
    const int b    = blockIdx.x;
    const int t    = threadIdx.x;
    const int wave = t >> 6;
    const int lane = t & 63;
    const int r0   = b * RPB;
    const float* __restrict__ s0 = scores + (size_t)r0 * SEGLEN;
    const float* __restrict__ s1 = s0 + SEGLEN;

    // kernel-2 atomicAdds into out; zero it here (stream order + kernel
    // boundary release make this coherent).
    if (b == 0 && t == 0) out[0] = 0.0f;

    // 16 coalesced nontemporal dwordx4 per thread, all issued before compute.
    f4 va[8], vb[8];
    #pragma unroll
    for (int k = 0; k < 8; ++k)
        va[k] = __builtin_nontemporal_load(((const f4*)s0) + (t + k * 256));
    #pragma unroll
    for (int k = 0; k < 8; ++k)
        vb[k] = __builtin_nontemporal_load(((const f4*)s1) + (t + k * 256));

    // Boundary table: sx[r][w][k] = v.x of lane 0 of wave w at iteration k.
    //   lane 63, wave w<3, iter k : next element = sx[r][w+1][k]
    //   lane 63, wave 3,   iter k : next element = sx[r][0][k+1]   (k<7)
    //   t=255, k=7 (last element of row): no diff -> v.w (d3 = 0)
    __shared__ float sx[RPB][4][8];
    if (lane == 0) {
        #pragma unroll
        for (int k = 0; k < 8; ++k) {
            sx[0][wave][k] = va[k].x;
            sx[1][wave][k] = vb[k].x;
        }
    }
    __syncthreads();

    float sum0 = 0.0f, sq0 = 0.0f, mv0 = -1.0f;  // scores in [0,1): -1 loses
    float sum1 = 0.0f, sq1 = 0.0f, mv1 = -1.0f;
    int   mi0 = SEGLEN, mi1 = SEGLEN;

    #pragma unroll
    for (int k = 0; k < 8; ++k) {
        const int c0 = (t + k * 256) * 4;     // element index of v[k].x

        float nxa = __shfl_down(va[k].x, 1);
        float nxb = __shfl_down(vb[k].x, 1);
        if (lane == 63) {
            nxa = (wave < 3) ? sx[0][wave + 1][k] : ((k < 7) ? sx[0][0][k + 1] : va[k].w);
            nxb = (wave < 3) ? sx[1][wave + 1][k] : ((k < 7) ? sx[1][0][k + 1] : vb[k].w);
        }

        { // row 0
            const float d0 = va[k].y - va[k].x;
            const float d1 = va[k].z - va[k].y;
            const float d2 = va[k].w - va[k].z;
            const float d3 = nxa     - va[k].w;
            sq0  += d0 * d0 + d1 * d1 + d2 * d2 + d3 * d3;
            sum0 += va[k].x + va[k].y + va[k].z + va[k].w;
            if (va[k].x > mv0) { mv0 = va[k].x; mi0 = c0;     }
            if (va[k].y > mv0) { mv0 = va[k].y; mi0 = c0 + 1; }
            if (va[k].z > mv0) { mv0 = va[k].z; mi0 = c0 + 2; }
            if (va[k].w > mv0) { mv0 = va[k].w; mi0 = c0 + 3; }
        }
        { // row 1
            const float d0 = vb[k].y - vb[k].x;
            const float d1 = vb[k].z - vb[k].y;
            const float d2 = vb[k].w - vb[k].z;
            const float d3 = nxb     - vb[k].w;
            sq1  += d0 * d0 + d1 * d1 + d2 * d2 + d3 * d3;
            sum1 += vb[k].x + vb[k].y + vb[k].z + vb[k].w;
            if (vb[k].x > mv1) { mv1 = vb[k].x; mi1 = c0;     }
            if (vb[k].y > mv1) { mv1 = vb[k].y; mi1 = c0 + 1; }
            if (vb[k].z > mv1) { mv1 = vb[k].z; mi1 = c0 + 2; }
            if (vb[k].w > mv1) { mv1 = vb[k].w; mi1 = c0 + 3; }
        }
    }

    // wave64 butterfly reduction, both rows
    #pragma unroll
    for (int off = 32; off > 0; off >>= 1) {
        sum0 += __shfl_xor(sum0, off);
        sq0  += __shfl_xor(sq0,  off);
        sum1 += __shfl_xor(sum1, off);
        sq1  += __shfl_xor(sq1,  off);
        const float ov0 = __shfl_xor(mv0, off);
        const int   oi0 = __shfl_xor(mi0, off);
        if (ov0 > mv0 || (ov0 == mv0 && oi0 < mi0)) { mv0 = ov0; mi0 = oi0; }
        const float ov1 = __shfl_xor(mv1, off);
        const int   oi1 = __shfl_xor(mi1, off);
        if (ov1 > mv1 || (ov1 == mv1 && oi1 < mi1)) { mv1 = ov1; mi1 = oi1; }
    }

    __shared__ float ssum[RPB][4], ssq[RPB][4], smv[RPB][4];
    __shared__ int   smi[RPB][4];
    if (lane == 0) {
        ssum[0][wave] = sum0; ssq[0][wave] = sq0; smv[0][wave] = mv0; smi[0][wave] = mi0;
        ssum[1][wave] = sum1; ssq[1][wave] = sq1; smv[1][wave] = mv1; smi[1][wave] = mi1;
    }
    __syncthreads();

    if (t == 0) {
        #pragma unroll
        for (int w = 1; w < 4; ++w) {
            sum0 += ssum[0][w];
            sq0  += ssq[0][w];
            if (smv[0][w] > mv0 || (smv[0][w] == mv0 && smi[0][w] < mi0)) { mv0 = smv[0][w]; mi0 = smi[0][w]; }
            sum1 += ssum[1][w];
            sq1  += ssq[1][w];
            if (smv[1][w] > mv1 || (smv[1][w] == mv1 && smi[1][w] < mi1)) { mv1 = smv[1][w]; mi1 = smi[1][w]; }
        }
        spars [r0]     = sum0;
        smooth[r0]     = sq0;
        ms    [r0]     = mi0;
        spars [r0 + 1] = sum1;
        smooth[r0 + 1] = sq1;
        ms    [r0 + 1] = mi1;
    }
}

// ---------------------------------------------------------------------------
// Kernel 2: margin + masked final sum. 256 blocks x 256 threads. UNCHANGED.
// Block b owns i in [b*16, b*16+16). ms[] and labels[] staged in LDS (32 KB).
// Grand sum over (i pos, j neg) pairs of relu(1 - ms[i] + ms[j]) plus the
// lambda terms for pos i; one float atomicAdd per block.
// Per-block int32 bound: 16 * 4096 * 8192 = 5.4e8 < INT_MAX.
// ---------------------------------------------------------------------------
#define MB_BLOCKS 256
#define IPB (BS / MB_BLOCKS)   // 16 rows per block

__global__ __launch_bounds__(256) void margin_final(const float* __restrict__ smooth,
                                                    const float* __restrict__ spars,
                                                    const int*   __restrict__ ms,
                                                    const int*   __restrict__ labels,
                                                    float*       __restrict__ out) {
    __shared__ int ms_l[BS];
    __shared__ int lab_l[BS];

    const int t = threadIdx.x;
    const int b = blockIdx.x;

    for (int idx = t; idx < BS; idx += 256) {
        ms_l[idx]  = ms[idx];
        lab_l[idx] = labels[idx];
    }
    __syncthreads();

    int   macc = 0;    // hinge sum over this block's pos-i rows
    float facc = 0.0f; // lambda terms for this block's pos-i rows

    #pragma unroll
    for (int ii = 0; ii < IPB; ++ii) {
        const int i = b * IPB + ii;
        if (lab_l[i] == 1) {
            const int base = 1 - ms_l[i];
            for (int j = t; j < BS; j += 256) {
                if (lab_l[j] == 0) {
                    const int v = base + ms_l[j];
                    macc += (v > 0) ? v : 0;
                }
            }
        }
    }
    if (t < IPB) {
        const int i = b * IPB + t;
        if (lab_l[i] == 1)
            facc = LAMBDA1 * smooth[i] + LAMBDA2 * spars[i];
    }

    // block reduction
    #pragma unroll
    for (int off = 32; off > 0; off >>= 1) {
        macc += __shfl_xor(macc, off);
        facc += __shfl_xor(facc, off);
    }
    __shared__ int   sacc[4];
    __shared__ float sfac[4];
    const int wave = t >> 6;
    if ((t & 63) == 0) { sacc[wave] = macc; sfac[wave] = facc; }
    __syncthreads();

    if (t == 0) {
        macc += sacc[1] + sacc[2] + sacc[3];
        facc += sfac[1] + sfac[2] + sfac[3];
        const float partial = (facc + (float)macc) * (1.0f / (float)BS);
        if (partial != 0.0f) atomicAdd(out, partial);
    }
}

extern "C" void kernel_launch(void* const* d_in, const int* in_sizes, int n_in,
                              void* d_out, int out_size, void* d_ws, size_t ws_size,
                              hipStream_t stream) {
    const float* scores = (const float*)d_in[0];
    const int*   labels = (const int*)d_in[1];
    float*       out    = (float*)d_out;

    float* smooth = (float*)d_ws;
    float* spars  = smooth + BS;
    int*   ms     = (int*)(spars + BS);

    row_stats<<<NB, 256, 0, stream>>>(scores, smooth, spars, ms, out);
    margin_final<<<MB_BLOCKS, 256, 0, stream>>>(smooth, spars, ms, labels, out);
}